// Round 1
// baseline (1863.254 us; speedup 1.0000x reference)
//
#include <hip/hip_runtime.h>
#include <math.h>

#define HWSZ (512*512)
#define WD 512
#define HD 512
#define CIN 64
#define EPSV 1e-5f

// ---------------------------------------------------------------------------
// Transpose dcn weights [o][c][3][3] -> [k][c][o]  (k = ky*3+kx)
// ---------------------------------------------------------------------------
__global__ __launch_bounds__(256) void transpose_w(const float* __restrict__ w,
                                                   float* __restrict__ wT) {
    int i = blockIdx.x * 256 + threadIdx.x;
    if (i >= 9 * 64 * 64) return;
    int k = i / 4096;
    int r = i % 4096;
    int c = r >> 6;
    int o = r & 63;
    wT[i] = w[(o * 64 + c) * 9 + k];
}

// ---------------------------------------------------------------------------
// 3x3 conv, 64 -> 18 channels, pad 1. 4 consecutive pixels per thread.
// Weight indices are wave-uniform -> scalar loads on the K$ pipe.
// ---------------------------------------------------------------------------
__global__ __launch_bounds__(256) void conv3x3_off(const float* __restrict__ in,
                                                   const float* __restrict__ w,
                                                   const float* __restrict__ b,
                                                   float* __restrict__ out) {
    int t = blockIdx.x * 256 + threadIdx.x;
    int p0 = t * 4;               // 4 consecutive pixels, same row (512 % 4 == 0)
    int y  = p0 >> 9;
    int x0 = p0 & 511;

    float acc[18][4];
#pragma unroll
    for (int o = 0; o < 18; ++o) {
        acc[o][0] = acc[o][1] = acc[o][2] = acc[o][3] = 0.f;
    }

    for (int c = 0; c < CIN; ++c) {
#pragma unroll
        for (int ky = 0; ky < 3; ++ky) {
            int ry = y + ky - 1;
            bool rv = (ry >= 0) && (ry < HD);
            const float* rp = in + c * HWSZ + ry * WD;
            float xr[6];
#pragma unroll
            for (int i = 0; i < 6; ++i) {
                int col = x0 - 1 + i;
                xr[i] = (rv && col >= 0 && col < WD) ? rp[col] : 0.f;
            }
#pragma unroll
            for (int kx = 0; kx < 3; ++kx) {
#pragma unroll
                for (int o = 0; o < 18; ++o) {
                    float wv = w[((o * CIN + c) * 3 + ky) * 3 + kx];  // uniform -> s_load
#pragma unroll
                    for (int px = 0; px < 4; ++px)
                        acc[o][px] = fmaf(wv, xr[kx + px], acc[o][px]);
                }
            }
        }
    }
#pragma unroll
    for (int o = 0; o < 18; ++o) {
        float bo = b[o];
        float4 v = make_float4(acc[o][0] + bo, acc[o][1] + bo,
                               acc[o][2] + bo, acc[o][3] + bo);
        *(float4*)(out + o * HWSZ + p0) = v;
    }
}

// ---------------------------------------------------------------------------
// Deformable conv 3x3 (64->64) + bias + BN + ReLU, fused.
// Block: 64-pixel row tile x all 64 out channels; 256 threads.
// Per tap: bilinear meta (validity folded into weights), sample S[c][p] into
// LDS, stage wT[k] tile in LDS, then 4o x 4p register-tiled FMA GEMM.
// ---------------------------------------------------------------------------
__global__ __launch_bounds__(256) void dcn_fused(const float* __restrict__ in,
                                                 const float* __restrict__ off,
                                                 const float* __restrict__ wT,
                                                 const float* __restrict__ bias,
                                                 const float* __restrict__ gamma,
                                                 const float* __restrict__ beta,
                                                 const float* __restrict__ mean,
                                                 const float* __restrict__ var,
                                                 float* __restrict__ out) {
    __shared__ float  S[64 * 64];    // sampled inputs [c][p]
    __shared__ float  WL[64 * 64];   // tap weights   [c][o]
    __shared__ float4 SW[64];        // bilinear weights per pixel
    __shared__ int4   SI[64];        // gather indices per pixel

    int tid   = threadIdx.x;
    int pbase = blockIdx.x * 64;     // 64 consecutive pixels, same row
    int pi = tid & 15;               // pixel quad
    int oi = tid >> 4;               // out-channel quad
    int sp = tid & 63;               // sampling: pixel
    int sc = tid >> 6;               // sampling: channel base

    float acc[4][4];
#pragma unroll
    for (int i = 0; i < 4; ++i)
#pragma unroll
        for (int j = 0; j < 4; ++j) acc[i][j] = 0.f;

    for (int k = 0; k < 9; ++k) {
        __syncthreads();  // previous tap's GEMM done before overwriting LDS

        if (tid < 64) {
            int pg = pbase + tid;
            int y = pg >> 9, x = pg & 511;
            float dy = off[(2 * k) * HWSZ + pg];
            float dx = off[(2 * k + 1) * HWSZ + pg];
            float py = (float)(y + k / 3 - 1) + dy;
            float px = (float)(x + k % 3 - 1) + dx;
            float y0f = floorf(py), x0f = floorf(px);
            float wy = py - y0f, wx = px - x0f;
            int y0 = (int)y0f, x0i = (int)x0f;
            int y1 = y0 + 1, x1 = x0i + 1;
            float vy0 = ((unsigned)y0  < 512u) ? 1.f : 0.f;
            float vy1 = ((unsigned)y1  < 512u) ? 1.f : 0.f;
            float vx0 = ((unsigned)x0i < 512u) ? 1.f : 0.f;
            float vx1 = ((unsigned)x1  < 512u) ? 1.f : 0.f;
            float w00 = (1.f - wy) * (1.f - wx) * vy0 * vx0;
            float w01 = (1.f - wy) * wx         * vy0 * vx1;
            float w10 = wy         * (1.f - wx) * vy1 * vx0;
            float w11 = wy         * wx         * vy1 * vx1;
            int y0c = min(max(y0, 0), 511), y1c = min(max(y1, 0), 511);
            int x0c = min(max(x0i, 0), 511), x1c = min(max(x1, 0), 511);
            SW[tid] = make_float4(w00, w01, w10, w11);
            SI[tid] = make_int4(y0c * WD + x0c, y0c * WD + x1c,
                                y1c * WD + x0c, y1c * WD + x1c);
        }
        // stage this tap's weight tile [c][o] into LDS (coalesced float4)
        {
            const float4* wsrc = (const float4*)(wT + k * 4096);
            float4* wdst = (float4*)WL;
#pragma unroll
            for (int j = 0; j < 4; ++j) wdst[tid + 256 * j] = wsrc[tid + 256 * j];
        }
        __syncthreads();

        // sampling: each thread does 16 (c,p) samples; lanes -> consecutive p
        {
            float4 wg = SW[sp];
            int4   id = SI[sp];
#pragma unroll
            for (int j = 0; j < 16; ++j) {
                int c = sc + 4 * j;
                const float* bp = in + c * HWSZ;
                float s = wg.x * bp[id.x] + wg.y * bp[id.y] +
                          wg.z * bp[id.z] + wg.w * bp[id.w];
                S[c * 64 + sp] = s;
            }
        }
        __syncthreads();

        // GEMM: acc[4o][4p] += WL[c][4o] * S[c][4p]
#pragma unroll 8
        for (int c = 0; c < 64; ++c) {
            float sv[4], wv[4];
            *(float4*)sv = *(const float4*)(S + c * 64 + 4 * pi);
            *(float4*)wv = *(const float4*)(WL + c * 64 + 4 * oi);
#pragma unroll
            for (int i = 0; i < 4; ++i)
#pragma unroll
                for (int j = 0; j < 4; ++j)
                    acc[i][j] = fmaf(wv[i], sv[j], acc[i][j]);
        }
    }

    // epilogue: +bias, BN, ReLU
#pragma unroll
    for (int i = 0; i < 4; ++i) {
        int o = 4 * oi + i;
        float scl = gamma[o] * rsqrtf(var[o] + EPSV);
        float sh  = beta[o] - mean[o] * scl + bias[o] * scl;
        float4 v;
        v.x = fmaxf(fmaf(acc[i][0], scl, sh), 0.f);
        v.y = fmaxf(fmaf(acc[i][1], scl, sh), 0.f);
        v.z = fmaxf(fmaf(acc[i][2], scl, sh), 0.f);
        v.w = fmaxf(fmaf(acc[i][3], scl, sh), 0.f);
        *(float4*)(out + o * HWSZ + pbase + 4 * pi) = v;
    }
}

// ---------------------------------------------------------------------------
// 1x1 conv 64 -> 1 + bias. Memory-bound, float4 per thread.
// ---------------------------------------------------------------------------
__global__ __launch_bounds__(256) void conv1x1_out(const float* __restrict__ in,
                                                   const float* __restrict__ w,
                                                   const float* __restrict__ b,
                                                   float* __restrict__ out) {
    int t = blockIdx.x * 256 + threadIdx.x;
    int p = t * 4;
    float bb = b[0];
    float4 acc = make_float4(bb, bb, bb, bb);
#pragma unroll 8
    for (int c = 0; c < 64; ++c) {
        float wc = w[c];  // uniform -> s_load
        float4 v = *(const float4*)(in + c * HWSZ + p);
        acc.x = fmaf(wc, v.x, acc.x);
        acc.y = fmaf(wc, v.y, acc.y);
        acc.z = fmaf(wc, v.z, acc.z);
        acc.w = fmaf(wc, v.w, acc.w);
    }
    *(float4*)(out + p) = acc;
}

// ---------------------------------------------------------------------------
extern "C" void kernel_launch(void* const* d_in, const int* in_sizes, int n_in,
                              void* d_out, int out_size, void* d_ws, size_t ws_size,
                              hipStream_t stream) {
    const float* x        = (const float*)d_in[0];
    const float* off1_w   = (const float*)d_in[1];
    const float* off1_b   = (const float*)d_in[2];
    const float* dcn1_w   = (const float*)d_in[3];
    const float* dcn1_b   = (const float*)d_in[4];
    const float* bn1_g    = (const float*)d_in[5];
    const float* bn1_be   = (const float*)d_in[6];
    const float* bn1_m    = (const float*)d_in[7];
    const float* bn1_v    = (const float*)d_in[8];
    const float* off2_w   = (const float*)d_in[9];
    const float* off2_b   = (const float*)d_in[10];
    const float* dcn2_w   = (const float*)d_in[11];
    const float* dcn2_b   = (const float*)d_in[12];
    const float* bn2_g    = (const float*)d_in[13];
    const float* bn2_be   = (const float*)d_in[14];
    const float* bn2_m    = (const float*)d_in[15];
    const float* bn2_v    = (const float*)d_in[16];
    const float* conv_w   = (const float*)d_in[17];
    const float* conv_b   = (const float*)d_in[18];
    float* out = (float*)d_out;

    // workspace layout (floats): h1 | h2 | off | wT1 | wT2  (~147 MiB total)
    float* ws  = (float*)d_ws;
    float* h1  = ws;
    float* h2  = ws + 16777216;
    float* off = ws + 2 * 16777216;
    float* wT1 = ws + 2 * 16777216 + 4718592;
    float* wT2 = wT1 + 36864;

    transpose_w<<<144, 256, 0, stream>>>(dcn1_w, wT1);
    transpose_w<<<144, 256, 0, stream>>>(dcn2_w, wT2);

    conv3x3_off<<<256, 256, 0, stream>>>(x, off1_w, off1_b, off);
    dcn_fused<<<4096, 256, 0, stream>>>(x, off, wT1, dcn1_b, bn1_g, bn1_be,
                                        bn1_m, bn1_v, h1);
    conv3x3_off<<<256, 256, 0, stream>>>(h1, off2_w, off2_b, off);
    dcn_fused<<<4096, 256, 0, stream>>>(h1, off, wT2, dcn2_b, bn2_g, bn2_be,
                                        bn2_m, bn2_v, h2);
    conv1x1_out<<<256, 256, 0, stream>>>(h2, conv_w, conv_b, out);
}

// Round 2
// 427.412 us; speedup vs baseline: 4.3594x; 4.3594x over previous
//
#include <hip/hip_runtime.h>
#include <math.h>

#define HWSZ (512*512)
#define WD 512
#define EPSV 1e-5f

typedef __bf16 bf16x8 __attribute__((ext_vector_type(8)));
typedef float  f32x4  __attribute__((ext_vector_type(4)));

__device__ __forceinline__ unsigned short f2bf(float f) {
    union { float f; unsigned u; } v; v.f = f;
    unsigned r = (v.u + 0x7fffu + ((v.u >> 16) & 1u)) >> 16;
    return (unsigned short)r;
}
__device__ __forceinline__ uint4 pack8(const float* s) {
    uint4 r;
    r.x = (unsigned)f2bf(s[0]) | ((unsigned)f2bf(s[1]) << 16);
    r.y = (unsigned)f2bf(s[2]) | ((unsigned)f2bf(s[3]) << 16);
    r.z = (unsigned)f2bf(s[4]) | ((unsigned)f2bf(s[5]) << 16);
    r.w = (unsigned)f2bf(s[6]) | ((unsigned)f2bf(s[7]) << 16);
    return r;
}
__device__ __forceinline__ bf16x8 as_frag(uint4 u) {
    return __builtin_bit_cast(bf16x8, u);
}

// ---------------------------------------------------------------------------
// NCHW -> HWC transpose (fp32), 64 px x 64 ch tile via LDS
// ---------------------------------------------------------------------------
__global__ __launch_bounds__(256) void to_hwc(const float* __restrict__ in,
                                              float* __restrict__ out) {
    __shared__ float T[64 * 65];
    int tid = threadIdx.x;
    int pbase = blockIdx.x * 64;
    int p = tid & 63;
    int cg = tid >> 6;
#pragma unroll
    for (int j = 0; j < 16; ++j) {
        int c = cg * 16 + j;
        T[p * 65 + c] = in[c * HWSZ + pbase + p];
    }
    __syncthreads();
#pragma unroll
    for (int j = 0; j < 16; ++j) {
        int pp = cg * 16 + j;
        out[(pbase + pp) * 64 + p] = T[pp * 65 + p];
    }
}

// ---------------------------------------------------------------------------
// dcn weights [o=64][c=64][3][3] fp32 -> wT[k][512] uint4: bf16, row o,
// channel-chunk cc stored at (cc ^ (o&7)), 8 bf16 per chunk.
// ---------------------------------------------------------------------------
__global__ __launch_bounds__(256) void prep_dcn_w(const float* __restrict__ w,
                                                  unsigned short* __restrict__ wT) {
    int i = blockIdx.x * 256 + threadIdx.x;
    if (i >= 9 * 64 * 64) return;
    int k = i / 4096, r = i % 4096;
    int o = r >> 6, c = r & 63;
    int dst = k * 4096 + (o * 8 + ((c >> 3) ^ (o & 7))) * 8 + (c & 7);
    wT[dst] = f2bf(w[(o * 64 + c) * 9 + k]);
}

// offset-conv weights [18][64][3][3] -> wTo[k][256] uint4 (32 rows, pad 0)
__global__ __launch_bounds__(256) void prep_off_w(const float* __restrict__ w,
                                                  unsigned short* __restrict__ wT) {
    int i = blockIdx.x * 256 + threadIdx.x;
    if (i >= 9 * 32 * 64) return;
    int k = i / 2048, r = i % 2048;
    int o = r >> 6, c = r & 63;
    float v = (o < 18) ? w[(o * 64 + c) * 9 + k] : 0.f;
    int dst = k * 2048 + (o * 8 + ((c >> 3) ^ (o & 7))) * 8 + (c & 7);
    wT[dst] = f2bf(v);
}

// ---------------------------------------------------------------------------
// 3x3 conv 64->18 (padded to 32) via MFMA. In: HWC fp32. Out: off[p][18].
// Block = 64 px x 32 n, K = 9 taps x 64 ch.
// ---------------------------------------------------------------------------
__global__ __launch_bounds__(256, 4) void conv3x3_off_mfma(
        const float* __restrict__ in, const uint4* __restrict__ wTo,
        const float* __restrict__ bias, float* __restrict__ off) {
    __shared__ uint4 Sl[512];    // S[px][c] bf16 swizzled
    __shared__ uint4 WLo[256];   // W[o=32][c] bf16 swizzled

    int tid = threadIdx.x;
    int pbase = blockIdx.x * 64;
    int l = tid & 63, wv = tid >> 6;
    int lq = l & 15, quad = l >> 4;
    int wn = wv & 1, wm = wv >> 1;   // wave tile: 32 px x 16 n

    f32x4 zero = {0.f, 0.f, 0.f, 0.f};
    f32x4 acc[2]; acc[0] = zero; acc[1] = zero;

    for (int k = 0; k < 9; ++k) {
        __syncthreads();
        if (tid < 256) WLo[tid] = wTo[k * 256 + tid];
        int ky = k / 3 - 1, kx = k % 3 - 1;
#pragma unroll
        for (int it = 0; it < 2; ++it) {
            int task = tid + 256 * it;
            int p = task >> 3, cc = task & 7;
            int gp = pbase + p;
            int sy = (gp >> 9) + ky, sx = (gp & 511) + kx;
            uint4 pk = make_uint4(0u, 0u, 0u, 0u);
            if ((unsigned)sy < 512u && (unsigned)sx < 512u) {
                const float4* sp = (const float4*)(in + (sy * 512 + sx) * 64 + cc * 8);
                float4 v0 = sp[0], v1 = sp[1];
                float s[8] = {v0.x, v0.y, v0.z, v0.w, v1.x, v1.y, v1.z, v1.w};
                pk = pack8(s);
            }
            Sl[p * 8 + (cc ^ (p & 7))] = pk;
        }
        __syncthreads();
#pragma unroll
        for (int kc = 0; kc < 2; ++kc) {
            int cc0 = kc * 4 + quad;
            bf16x8 a0 = as_frag(Sl[(wm * 32 + lq) * 8 + (cc0 ^ (lq & 7))]);
            bf16x8 a1 = as_frag(Sl[(wm * 32 + 16 + lq) * 8 + (cc0 ^ (lq & 7))]);
            bf16x8 b0 = as_frag(WLo[(wn * 16 + lq) * 8 + (cc0 ^ (lq & 7))]);
            acc[0] = __builtin_amdgcn_mfma_f32_16x16x32_bf16(a0, b0, acc[0], 0, 0, 0);
            acc[1] = __builtin_amdgcn_mfma_f32_16x16x32_bf16(a1, b0, acc[1], 0, 0, 0);
        }
    }

    int n = wn * 16 + lq;
    if (n < 18) {
        float bb = bias[n];
#pragma unroll
        for (int tm = 0; tm < 2; ++tm)
#pragma unroll
            for (int reg = 0; reg < 4; ++reg) {
                int px = wm * 32 + tm * 16 + quad * 4 + reg;
                off[(pbase + px) * 18 + n] = acc[tm][reg] + bb;
            }
    }
}

// ---------------------------------------------------------------------------
// Deformable conv 3x3 64->64 + bias + BN + ReLU via MFMA.
// In: HWC fp32, off[p][18]. Out: HWC fp32.
// Block = 64 px x 64 oc; per tap: coalesced bilinear gather -> bf16 LDS,
// then 16x16x32 MFMA GEMM (4 waves x 32x32 tiles).
// ---------------------------------------------------------------------------
__global__ __launch_bounds__(256, 4) void dcn_fused(
        const float* __restrict__ in, const float* __restrict__ off,
        const uint4* __restrict__ wT, const float* __restrict__ bias,
        const float* __restrict__ gamma, const float* __restrict__ beta,
        const float* __restrict__ mean, const float* __restrict__ var,
        float* __restrict__ out) {
    __shared__ uint4  Sl[512];        // S[px][c] bf16 swizzled
    __shared__ uint4  WLl[512];       // W[o][c]  bf16 swizzled
    __shared__ float4 SW9[9 * 64];    // bilinear weights
    __shared__ int4   SI9[9 * 64];    // corner base offsets (HWC floats)
    __shared__ float  scl_s[64], sh_s[64];

    int tid = threadIdx.x;
    int pbase = blockIdx.x * 64;

    // per-pixel meta for all 9 taps
    for (int t = tid; t < 576; t += 256) {
        int p = t & 63, k = t >> 6;
        int gp = pbase + p;
        int y = gp >> 9, x = gp & 511;
        float dy = off[gp * 18 + 2 * k];
        float dx = off[gp * 18 + 2 * k + 1];
        float py = (float)(y + k / 3 - 1) + dy;
        float px = (float)(x + k % 3 - 1) + dx;
        float y0f = floorf(py), x0f = floorf(px);
        float wy = py - y0f, wx = px - x0f;
        int y0 = (int)y0f, x0 = (int)x0f;
        int y1 = y0 + 1, x1 = x0 + 1;
        float vy0 = ((unsigned)y0 < 512u) ? 1.f : 0.f;
        float vy1 = ((unsigned)y1 < 512u) ? 1.f : 0.f;
        float vx0 = ((unsigned)x0 < 512u) ? 1.f : 0.f;
        float vx1 = ((unsigned)x1 < 512u) ? 1.f : 0.f;
        SW9[t] = make_float4((1.f - wy) * (1.f - wx) * vy0 * vx0,
                             (1.f - wy) * wx * vy0 * vx1,
                             wy * (1.f - wx) * vy1 * vx0,
                             wy * wx * vy1 * vx1);
        int y0c = min(max(y0, 0), 511), y1c = min(max(y1, 0), 511);
        int x0c = min(max(x0, 0), 511), x1c = min(max(x1, 0), 511);
        SI9[t] = make_int4((y0c * 512 + x0c) * 64, (y0c * 512 + x1c) * 64,
                           (y1c * 512 + x0c) * 64, (y1c * 512 + x1c) * 64);
    }
    if (tid < 64) {
        float s = gamma[tid] * rsqrtf(var[tid] + EPSV);
        scl_s[tid] = s;
        sh_s[tid] = beta[tid] - mean[tid] * s + bias[tid] * s;
    }

    int l = tid & 63, wv = tid >> 6;
    int lq = l & 15, quad = l >> 4;
    int wm = wv & 1, wn = wv >> 1;    // wave tile: 32 px x 32 oc

    f32x4 zero = {0.f, 0.f, 0.f, 0.f};
    f32x4 acc[2][2];
    acc[0][0] = zero; acc[0][1] = zero; acc[1][0] = zero; acc[1][1] = zero;

    for (int k = 0; k < 9; ++k) {
        __syncthreads();
        WLl[tid]       = wT[k * 512 + tid];
        WLl[tid + 256] = wT[k * 512 + tid + 256];
#pragma unroll
        for (int it = 0; it < 2; ++it) {
            int task = tid + 256 * it;
            int p = task >> 3, cc = task & 7;
            float4 wg = SW9[k * 64 + p];
            int4   id = SI9[k * 64 + p];
            const float4* c00 = (const float4*)(in + id.x + cc * 8);
            const float4* c01 = (const float4*)(in + id.y + cc * 8);
            const float4* c10 = (const float4*)(in + id.z + cc * 8);
            const float4* c11 = (const float4*)(in + id.w + cc * 8);
            float4 va = c00[0], vb = c00[1];
            float s[8];
            s[0] = wg.x * va.x; s[1] = wg.x * va.y; s[2] = wg.x * va.z; s[3] = wg.x * va.w;
            s[4] = wg.x * vb.x; s[5] = wg.x * vb.y; s[6] = wg.x * vb.z; s[7] = wg.x * vb.w;
            va = c01[0]; vb = c01[1];
            s[0] = fmaf(wg.y, va.x, s[0]); s[1] = fmaf(wg.y, va.y, s[1]);
            s[2] = fmaf(wg.y, va.z, s[2]); s[3] = fmaf(wg.y, va.w, s[3]);
            s[4] = fmaf(wg.y, vb.x, s[4]); s[5] = fmaf(wg.y, vb.y, s[5]);
            s[6] = fmaf(wg.y, vb.z, s[6]); s[7] = fmaf(wg.y, vb.w, s[7]);
            va = c10[0]; vb = c10[1];
            s[0] = fmaf(wg.z, va.x, s[0]); s[1] = fmaf(wg.z, va.y, s[1]);
            s[2] = fmaf(wg.z, va.z, s[2]); s[3] = fmaf(wg.z, va.w, s[3]);
            s[4] = fmaf(wg.z, vb.x, s[4]); s[5] = fmaf(wg.z, vb.y, s[5]);
            s[6] = fmaf(wg.z, vb.z, s[6]); s[7] = fmaf(wg.z, vb.w, s[7]);
            va = c11[0]; vb = c11[1];
            s[0] = fmaf(wg.w, va.x, s[0]); s[1] = fmaf(wg.w, va.y, s[1]);
            s[2] = fmaf(wg.w, va.z, s[2]); s[3] = fmaf(wg.w, va.w, s[3]);
            s[4] = fmaf(wg.w, vb.x, s[4]); s[5] = fmaf(wg.w, vb.y, s[5]);
            s[6] = fmaf(wg.w, vb.z, s[6]); s[7] = fmaf(wg.w, vb.w, s[7]);
            Sl[p * 8 + (cc ^ (p & 7))] = pack8(s);
        }
        __syncthreads();
#pragma unroll
        for (int kc = 0; kc < 2; ++kc) {
            int cc0 = kc * 4 + quad;
            bf16x8 a0 = as_frag(Sl[(wm * 32 + lq) * 8 + (cc0 ^ (lq & 7))]);
            bf16x8 a1 = as_frag(Sl[(wm * 32 + 16 + lq) * 8 + (cc0 ^ (lq & 7))]);
            bf16x8 b0 = as_frag(WLl[(wn * 32 + lq) * 8 + (cc0 ^ (lq & 7))]);
            bf16x8 b1 = as_frag(WLl[(wn * 32 + 16 + lq) * 8 + (cc0 ^ (lq & 7))]);
            acc[0][0] = __builtin_amdgcn_mfma_f32_16x16x32_bf16(a0, b0, acc[0][0], 0, 0, 0);
            acc[0][1] = __builtin_amdgcn_mfma_f32_16x16x32_bf16(a0, b1, acc[0][1], 0, 0, 0);
            acc[1][0] = __builtin_amdgcn_mfma_f32_16x16x32_bf16(a1, b0, acc[1][0], 0, 0, 0);
            acc[1][1] = __builtin_amdgcn_mfma_f32_16x16x32_bf16(a1, b1, acc[1][1], 0, 0, 0);
        }
    }

    float sc0 = scl_s[wn * 32 + lq],      sh0 = sh_s[wn * 32 + lq];
    float sc1 = scl_s[wn * 32 + 16 + lq], sh1 = sh_s[wn * 32 + 16 + lq];
#pragma unroll
    for (int tm = 0; tm < 2; ++tm)
#pragma unroll
        for (int reg = 0; reg < 4; ++reg) {
            int px = wm * 32 + tm * 16 + quad * 4 + reg;
            float* op = out + (pbase + px) * 64 + wn * 32 + lq;
            op[0]  = fmaxf(fmaf(acc[tm][0][reg], sc0, sh0), 0.f);
            op[16] = fmaxf(fmaf(acc[tm][1][reg], sc1, sh1), 0.f);
        }
}

// ---------------------------------------------------------------------------
// 1x1 conv 64->1 + bias (HWC input)
// ---------------------------------------------------------------------------
__global__ __launch_bounds__(256) void conv1x1_out(const float* __restrict__ in,
                                                   const float* __restrict__ w,
                                                   const float* __restrict__ b,
                                                   float* __restrict__ out) {
    int p = blockIdx.x * 256 + threadIdx.x;
    float acc = b[0];
    const float4* ip = (const float4*)(in + p * 64);
    const float4* wp = (const float4*)w;
#pragma unroll
    for (int j = 0; j < 16; ++j) {
        float4 v = ip[j], wv = wp[j];
        acc = fmaf(v.x, wv.x, acc); acc = fmaf(v.y, wv.y, acc);
        acc = fmaf(v.z, wv.z, acc); acc = fmaf(v.w, wv.w, acc);
    }
    out[p] = acc;
}

// ---------------------------------------------------------------------------
extern "C" void kernel_launch(void* const* d_in, const int* in_sizes, int n_in,
                              void* d_out, int out_size, void* d_ws, size_t ws_size,
                              hipStream_t stream) {
    const float* x      = (const float*)d_in[0];
    const float* off1_w = (const float*)d_in[1];
    const float* off1_b = (const float*)d_in[2];
    const float* dcn1_w = (const float*)d_in[3];
    const float* dcn1_b = (const float*)d_in[4];
    const float* bn1_g  = (const float*)d_in[5];
    const float* bn1_be = (const float*)d_in[6];
    const float* bn1_m  = (const float*)d_in[7];
    const float* bn1_v  = (const float*)d_in[8];
    const float* off2_w = (const float*)d_in[9];
    const float* off2_b = (const float*)d_in[10];
    const float* dcn2_w = (const float*)d_in[11];
    const float* dcn2_b = (const float*)d_in[12];
    const float* bn2_g  = (const float*)d_in[13];
    const float* bn2_be = (const float*)d_in[14];
    const float* bn2_m  = (const float*)d_in[15];
    const float* bn2_v  = (const float*)d_in[16];
    const float* conv_w = (const float*)d_in[17];
    const float* conv_b = (const float*)d_in[18];
    float* out = (float*)d_out;

    float* ws  = (float*)d_ws;
    float* xh  = ws;                       // 16,777,216 floats (also reused as h2)
    float* h1  = ws + 16777216;            // 16,777,216 floats
    float* off = ws + 2 * 16777216;        //  4,718,592 floats
    unsigned short* wT1  = (unsigned short*)(ws + 38273024);  // 36864 bf16
    unsigned short* wT2  = wT1 + 36864;
    unsigned short* wTo1 = wT2 + 36864;                       // 18432 bf16
    unsigned short* wTo2 = wTo1 + 18432;
    float* h2 = xh;

    prep_dcn_w<<<144, 256, 0, stream>>>(dcn1_w, wT1);
    prep_dcn_w<<<144, 256, 0, stream>>>(dcn2_w, wT2);
    prep_off_w<<<72, 256, 0, stream>>>(off1_w, wTo1);
    prep_off_w<<<72, 256, 0, stream>>>(off2_w, wTo2);
    to_hwc<<<4096, 256, 0, stream>>>(x, xh);

    conv3x3_off_mfma<<<4096, 256, 0, stream>>>(xh, (const uint4*)wTo1, off1_b, off);
    dcn_fused<<<4096, 256, 0, stream>>>(xh, off, (const uint4*)wT1, dcn1_b,
                                        bn1_g, bn1_be, bn1_m, bn1_v, h1);
    conv3x3_off_mfma<<<4096, 256, 0, stream>>>(h1, (const uint4*)wTo2, off2_b, off);
    dcn_fused<<<4096, 256, 0, stream>>>(h1, off, (const uint4*)wT2, dcn2_b,
                                        bn2_g, bn2_be, bn2_m, bn2_v, h2);
    conv1x1_out<<<1024, 256, 0, stream>>>(h2, conv_w, conv_b, out);
}